// Round 5
// baseline (1127.799 us; speedup 1.0000x reference)
//
#include <hip/hip_runtime.h>
#include <stdint.h>

// BitNet b1.58 column-parallel linear:
//   y[m,n] = (sum_k qx[m,k]*qw[n,k]) * inv_sx[m] * inv_sw + bias[n]
// M=8192 (B*S), N=16384 (D_OUT), K=4096 (D_IN)

#define M_ROWS 8192
#define N_COLS 16384
#define K_DIM  4096
#define NT     (K_DIM / 64)   // 64 K-steps of 64 bytes

typedef int v4i  __attribute__((ext_vector_type(4)));
typedef int v16i __attribute__((ext_vector_type(16)));

// ---------------- workspace layout ----------------
#define WS_PARTIALS 0
#define WS_PARAMS   8192
#define WS_INVSX    8448
#define WS_QX       41216
#define WS_QW       (41216 + 33554432)
#define WS_NEED     ((size_t)WS_QW + 67108864)

// ---------------- activation quant: per-row int8 absmax ----------------
__device__ __forceinline__ int quant_act1(float v, float s) {
    float q = rintf(v * s);               // round-half-even, matches jnp.round
    q = fminf(127.0f, fmaxf(-128.0f, q));
    return (int)q;
}

__global__ __launch_bounds__(256) void act_quant_kernel(const float* __restrict__ x,
                                                        int8_t* __restrict__ qx,
                                                        float* __restrict__ inv_sx) {
    const int row = blockIdx.x;
    const int t = threadIdx.x;
    const float4* xr = (const float4*)(x + (size_t)row * K_DIM);

    float4 v[4];
    float m = 0.0f;
#pragma unroll
    for (int i = 0; i < 4; ++i) {
        v[i] = xr[t + 256 * i];
        m = fmaxf(m, fmaxf(fmaxf(fabsf(v[i].x), fabsf(v[i].y)),
                           fmaxf(fabsf(v[i].z), fabsf(v[i].w))));
    }
#pragma unroll
    for (int off = 32; off > 0; off >>= 1) m = fmaxf(m, __shfl_xor(m, off));
    __shared__ float wm[4];
    if ((t & 63) == 0) wm[t >> 6] = m;
    __syncthreads();
    m = fmaxf(fmaxf(wm[0], wm[1]), fmaxf(wm[2], wm[3]));
    m = fmaxf(m, 1e-5f);                  // clip(max, EPS)
    const float scale = 127.0f / m;
    if (t == 0) inv_sx[row] = 1.0f / scale;

    int* qr = (int*)(qx + (size_t)row * K_DIM);
#pragma unroll
    for (int i = 0; i < 4; ++i) {
        int b0 = quant_act1(v[i].x, scale) & 255;
        int b1 = quant_act1(v[i].y, scale) & 255;
        int b2 = quant_act1(v[i].z, scale) & 255;
        int b3 = quant_act1(v[i].w, scale) & 255;
        qr[t + 256 * i] = b0 | (b1 << 8) | (b2 << 16) | (b3 << 24);
    }
}

// ---------------- weight abs-sum (deterministic two-stage) ----------------
__global__ __launch_bounds__(256) void wabs_partial_kernel(const float* __restrict__ w,
                                                           float* __restrict__ partials) {
    const int t = threadIdx.x;
    const size_t base = (size_t)blockIdx.x * 8192;   // float4 units
    const float4* w4 = (const float4*)w;
    float s = 0.0f;
#pragma unroll 8
    for (int i = 0; i < 32; ++i) {
        float4 v = w4[base + (size_t)i * 256 + t];
        s += fabsf(v.x) + fabsf(v.y) + fabsf(v.z) + fabsf(v.w);
    }
#pragma unroll
    for (int off = 32; off > 0; off >>= 1) s += __shfl_xor(s, off);
    __shared__ float wp[4];
    if ((t & 63) == 0) wp[t >> 6] = s;
    __syncthreads();
    if (t == 0) partials[blockIdx.x] = (wp[0] + wp[1]) + (wp[2] + wp[3]);
}

__global__ __launch_bounds__(256) void wfinal_kernel(const float* __restrict__ partials,
                                                     float* __restrict__ params) {
    __shared__ double sh[256];
    const int t = threadIdx.x;
    double s = 0.0;
    for (int i = t; i < 2048; i += 256) s += (double)partials[i];
    sh[t] = s;
    __syncthreads();
    for (int off = 128; off > 0; off >>= 1) {
        if (t < off) sh[t] += sh[t + off];
        __syncthreads();
    }
    if (t == 0) {
        float mean = (float)(sh[0] / 67108864.0);
        mean = fmaxf(mean, 1e-5f);        // clip(mean, EPS)
        float scale = 1.0f / mean;        // scale_w
        params[0] = scale;
        params[1] = 1.0f / scale;         // inv_sw
    }
}

// ---------------- weight quant: per-tensor ternary ----------------
__device__ __forceinline__ int quant_w1(float v, float s) {
    float q = rintf(v * s);
    q = fminf(1.0f, fmaxf(-1.0f, q));
    return (int)q;
}

__global__ __launch_bounds__(256) void w_quant_kernel(const float* __restrict__ w,
                                                      int8_t* __restrict__ qw,
                                                      const float* __restrict__ params) {
    const float scale = params[0];
    const int stride = gridDim.x * 256;
    const float4* w4 = (const float4*)w;
    int* q4 = (int*)qw;
    for (int g = blockIdx.x * 256 + threadIdx.x; g < 16777216; g += stride) {
        float4 v = w4[g];
        int b0 = quant_w1(v.x, scale) & 255;
        int b1 = quant_w1(v.y, scale) & 255;
        int b2 = quant_w1(v.z, scale) & 255;
        int b3 = quant_w1(v.w, scale) & 255;
        q4[g] = b0 | (b1 << 8) | (b2 << 16) | (b3 << 24);
    }
}

// ---------------- int8 GEMM: 256x256, mfma_i32_32x32x32, 1 barrier/K-step, stage-3-ahead --
// 8 waves (2M x 4N), per-wave 128x64 output = 4 m-tiles x 2 n-tiles of 32x32.
// 4-slot LDS ring (slot = ks&3). Half(t): issue next K-step's 12 ds_reads (slot t+1,
// published at entry barrier), GLD4(t+3), two counted lgkmcnt(12) waits, 2x 8-MFMA
// clusters, vmcnt(4) [proves t+2 landed], s_barrier [publishes t+2].
// Reads run a full half-iter ahead under the MFMA stream; never drain in main loop.
// 16B-chunk XOR swizzle on both global source and ds_read address (verified: 0 conflicts).
__global__ __launch_bounds__(512, 2) void gemm_i8_kernel(const int8_t* __restrict__ qx,
                                                         const int8_t* __restrict__ qw,
                                                         const float* __restrict__ inv_sx,
                                                         const float* __restrict__ params,
                                                         const float* __restrict__ bias,
                                                         float* __restrict__ y) {
    __shared__ __align__(16) int8_t As[4][16384];
    __shared__ __align__(16) int8_t Bs[4][16384];
    int8_t* AsB = &As[0][0];
    int8_t* BsB = &Bs[0][0];

    const int tid = threadIdx.x;
    const int lane = tid & 63;
    const int w = tid >> 6;           // wave 0..7
    const int wr = w >> 2;            // 0..1  (M half)
    const int wc = w & 3;             // 0..3  (N quarter)
    const int wbase = w * 1024;       // wave-uniform LDS staging base (64 lanes x 16B)

    // XCD-aware bijective swizzle: 2048 blocks, 8 XCDs
    const int bid = blockIdx.x;
    const int swz = (bid & 7) * 256 + (bid >> 3);
    const int bn = swz & 63;          // 64 n-blocks
    const int bm = swz >> 6;          // 32 m-blocks

    const size_t arow0 = (size_t)bm * 256;
    const size_t brow0 = (size_t)bn * 256;

    // staging addressing: 512 chunks of 16B per 128-row half; thread tid -> chunk tid
    const int r0 = tid >> 2;                       // row 0..127 within half
    const int kc0 = (tid & 3) ^ ((r0 >> 1) & 3);   // swizzled k-slot (involution)
    const int8_t* gA0 = qx + (arow0 + r0) * K_DIM + kc0 * 16;
    const int8_t* gA1 = gA0 + (size_t)128 * K_DIM;
    const int8_t* gB0 = qw + (brow0 + r0) * K_DIM + kc0 * 16;
    const int8_t* gB1 = gB0 + (size_t)128 * K_DIM;

#define GLD(g, l)                                                                        \
    __builtin_amdgcn_global_load_lds((const __attribute__((address_space(1))) void*)(g), \
                                     (__attribute__((address_space(3))) void*)(l), 16, 0, 0)

#define GLD4(ks, SLOT)                                                                   \
    do {                                                                                 \
        const size_t _o = (size_t)(ks) * 64;                                             \
        GLD(gA0 + _o, AsB + (SLOT) * 16384 + wbase);                                     \
        GLD(gA1 + _o, AsB + (SLOT) * 16384 + 8192 + wbase);                              \
        GLD(gB0 + _o, BsB + (SLOT) * 16384 + wbase);                                     \
        GLD(gB1 + _o, BsB + (SLOT) * 16384 + 8192 + wbase);                              \
    } while (0)

    // fragment ds_read offsets for 32x32x32: lane holds row (lane&31),
    // k-bytes (lane>>5)*16 within each 32B k-half.
    const int l31 = lane & 31;
    const int lh = lane >> 5;         // 0..1
    int aoff[4][2], boff[2][2];
#pragma unroll
    for (int m = 0; m < 4; ++m) {
        const int ra = wr * 128 + m * 32 + l31;
#pragma unroll
        for (int kh = 0; kh < 2; ++kh) {
            const int s = (kh * 2 + lh) ^ ((ra >> 1) & 3);
            aoff[m][kh] = ra * 64 + s * 16;
        }
    }
#pragma unroll
    for (int n = 0; n < 2; ++n) {
        const int rb = wc * 64 + n * 32 + l31;
#pragma unroll
        for (int kh = 0; kh < 2; ++kh) {
            const int s = (kh * 2 + lh) ^ ((rb >> 1) & 3);
            boff[n][kh] = rb * 64 + s * 16;
        }
    }

    v16i acc[4][2];
#pragma unroll
    for (int m = 0; m < 4; ++m)
#pragma unroll
        for (int n = 0; n < 2; ++n) acc[m][n] = (v16i)(0);

    // two alternating fragment sets (E = even K-step, O = odd K-step)
    v4i Ea0[4], Ea1[4], Oa0[4], Oa1[4];
    v4i Eb0[2], Eb1[2], Ob0[2], Ob1[2];

#define RDA(dst, base_, kh)                                                    \
    do {                                                                       \
        _Pragma("unroll") for (int _m = 0; _m < 4; ++_m)                       \
            dst[_m] = *(const v4i*)((base_) + aoff[_m][kh]);                   \
    } while (0)
#define RDB(dst, base_, kh)                                                    \
    do {                                                                       \
        _Pragma("unroll") for (int _n = 0; _n < 2; ++_n)                       \
            dst[_n] = *(const v4i*)((base_) + boff[_n][kh]);                   \
    } while (0)

#define MF8(A_, B_)                                                            \
    do {                                                                       \
        __builtin_amdgcn_s_setprio(1);                                         \
        _Pragma("unroll") for (int _m = 0; _m < 4; ++_m)                       \
            _Pragma("unroll") for (int _n = 0; _n < 2; ++_n)                   \
                acc[_m][_n] = __builtin_amdgcn_mfma_i32_32x32x32_i8(           \
                    A_[_m], B_[_n], acc[_m][_n], 0, 0, 0);                     \
        __builtin_amdgcn_s_setprio(0);                                         \
    } while (0)

#define WAITL(NSTR)                                                            \
    do {                                                                       \
        __builtin_amdgcn_sched_barrier(0);                                     \
        asm volatile("s_waitcnt lgkmcnt(" NSTR ")" ::: "memory");              \
        __builtin_amdgcn_sched_barrier(0);                                     \
    } while (0)
#define VM4() asm volatile("s_waitcnt vmcnt(4)" ::: "memory")
#define VM0() asm volatile("s_waitcnt vmcnt(0)" ::: "memory")
#define BARR()                                                                 \
    do {                                                                       \
        __builtin_amdgcn_s_barrier();                                          \
        __builtin_amdgcn_sched_barrier(0);                                     \
    } while (0)

// One K-step: compute C-set (loaded last half), prefetch N-set from slot NXT.
// STG = staging statement (or nothing), END = vm+barrier statements (or nothing).
#define HALF(CA0, CB0, CA1, CB1, NA0, NB0, NA1, NB1, NXT, STG, END)            \
    do {                                                                       \
        RDA(NA0, AsB + (NXT) * 16384, 0);                                      \
        RDB(NB0, BsB + (NXT) * 16384, 0);                                      \
        STG;                                                                   \
        WAITL("12");   /* all but {N*0, prev-half N*1} done -> C*0 ready */    \
        MF8(CA0, CB0);                                                         \
        RDA(NA1, AsB + (NXT) * 16384, 1);                                      \
        RDB(NB1, BsB + (NXT) * 16384, 1);                                      \
        WAITL("12");   /* -> C*1 ready */                                      \
        MF8(CA1, CB1);                                                         \
        END;                                                                   \
    } while (0)

    // prologue: stage K-steps 0,1,2; publish slot 0; load E-set; publish slot 1
    GLD4(0, 0);
    GLD4(1, 1);
    GLD4(2, 2);
    asm volatile("s_waitcnt vmcnt(8)" ::: "memory");   // K-step 0 landed
    BARR();
    RDA(Ea0, AsB, 0);
    RDB(Eb0, BsB, 0);
    RDA(Ea1, AsB, 1);
    RDB(Eb1, BsB, 1);
    asm volatile("s_waitcnt vmcnt(4)" ::: "memory");   // K-step 1 landed
    BARR();

    // main loop: 15 iters x 4 K-steps (t = 4j .. 4j+3), stages 4j+3 .. 4j+6
#pragma unroll 1
    for (int j = 0; j < 15; ++j) {
        const int tb = 4 * j;
        HALF(Ea0, Eb0, Ea1, Eb1, Oa0, Ob0, Oa1, Ob1, 1, GLD4(tb + 3, 3), VM4(); BARR());
        HALF(Oa0, Ob0, Oa1, Ob1, Ea0, Eb0, Ea1, Eb1, 2, GLD4(tb + 4, 0), VM4(); BARR());
        HALF(Ea0, Eb0, Ea1, Eb1, Oa0, Ob0, Oa1, Ob1, 3, GLD4(tb + 5, 1), VM4(); BARR());
        HALF(Oa0, Ob0, Oa1, Ob1, Ea0, Eb0, Ea1, Eb1, 0, GLD4(tb + 6, 2), VM4(); BARR());
    }
    // tail: K-steps 60..63 (slots 0..3; 60,61,62 already staged; stage 63 in half 60)
    HALF(Ea0, Eb0, Ea1, Eb1, Oa0, Ob0, Oa1, Ob1, 1, GLD4(63, 3), VM4(); BARR()); // t=60, pub 62
    HALF(Oa0, Ob0, Oa1, Ob1, Ea0, Eb0, Ea1, Eb1, 2, , VM0(); BARR());            // t=61, pub 63
    HALF(Ea0, Eb0, Ea1, Eb1, Oa0, Ob0, Oa1, Ob1, 3, , );                         // t=62
    WAITL("0");                                                                  // t=63
    MF8(Oa0, Ob0);
    MF8(Oa1, Ob1);

    // epilogue: y = acc * inv_sx[row] * inv_sw + bias[col]
    // 32x32 C/D: col = lane&31, row = (g&3) + 8*(g>>2) + 4*(lane>>5)
    const float invsw = params[1];
#pragma unroll
    for (int m = 0; m < 4; ++m) {
        const int rb = (int)arow0 + wr * 128 + m * 32 + 4 * lh;
        float isx[16];
#pragma unroll
        for (int g = 0; g < 16; ++g)
            isx[g] = inv_sx[rb + 8 * (g >> 2) + (g & 3)] * invsw;
#pragma unroll
        for (int n = 0; n < 2; ++n) {
            const int gcol = (int)brow0 + wc * 64 + n * 32 + l31;
            const float bb = bias[gcol];
#pragma unroll
            for (int g = 0; g < 16; ++g) {
                const int grow = rb + 8 * (g >> 2) + (g & 3);
                y[(size_t)grow * N_COLS + gcol] = (float)acc[m][n][g] * isx[g] + bb;
            }
        }
    }
#undef GLD
#undef GLD4
#undef RDA
#undef RDB
#undef MF8
#undef WAITL
#undef VM4
#undef VM0
#undef BARR
#undef HALF
}

// ---------------- launch ----------------
extern "C" void kernel_launch(void* const* d_in, const int* in_sizes, int n_in,
                              void* d_out, int out_size, void* d_ws, size_t ws_size,
                              hipStream_t stream) {
    const float* x    = (const float*)d_in[0];
    const float* wt   = (const float*)d_in[1];
    const float* bias = (const float*)d_in[2];
    float* y = (float*)d_out;

    if (ws_size < WS_NEED) return;

    char* ws = (char*)d_ws;
    float* partials = (float*)(ws + WS_PARTIALS);
    float* params   = (float*)(ws + WS_PARAMS);
    float* inv_sx   = (float*)(ws + WS_INVSX);
    int8_t* qx = (int8_t*)(ws + WS_QX);
    int8_t* qw = (int8_t*)(ws + WS_QW);

    hipLaunchKernelGGL(act_quant_kernel,   dim3(8192), dim3(256), 0, stream, x, qx, inv_sx);
    hipLaunchKernelGGL(wabs_partial_kernel,dim3(2048), dim3(256), 0, stream, wt, partials);
    hipLaunchKernelGGL(wfinal_kernel,      dim3(1),    dim3(256), 0, stream, partials, params);
    hipLaunchKernelGGL(w_quant_kernel,     dim3(4096), dim3(256), 0, stream, wt, qw, params);
    hipLaunchKernelGGL(gemm_i8_kernel,     dim3(2048), dim3(512), 0, stream,
                       qx, qw, inv_sx, params, bias, y);
}

// Round 6
// 746.857 us; speedup vs baseline: 1.5101x; 1.5101x over previous
//
#include <hip/hip_runtime.h>
#include <stdint.h>

// BitNet b1.58 column-parallel linear:
//   y[m,n] = (sum_k qx[m,k]*qw[n,k]) * inv_sx[m] * inv_sw + bias[n]
// M=8192 (B*S), N=16384 (D_OUT), K=4096 (D_IN)

#define M_ROWS 8192
#define N_COLS 16384
#define K_DIM  4096
#define NT     (K_DIM / 64)   // 64 K-steps of 64 bytes

typedef int v4i __attribute__((ext_vector_type(4)));

// ---------------- workspace layout ----------------
#define WS_PARTIALS 0
#define WS_PARAMS   8192
#define WS_INVSX    8448
#define WS_QX       41216
#define WS_QW       (41216 + 33554432)
#define WS_NEED     ((size_t)WS_QW + 67108864)

// ---------------- activation quant: per-row int8 absmax ----------------
__device__ __forceinline__ int quant_act1(float v, float s) {
    float q = rintf(v * s);               // round-half-even, matches jnp.round
    q = fminf(127.0f, fmaxf(-128.0f, q));
    return (int)q;
}

__global__ __launch_bounds__(256) void act_quant_kernel(const float* __restrict__ x,
                                                        int8_t* __restrict__ qx,
                                                        float* __restrict__ inv_sx) {
    const int row = blockIdx.x;
    const int t = threadIdx.x;
    const float4* xr = (const float4*)(x + (size_t)row * K_DIM);

    float4 v[4];
    float m = 0.0f;
#pragma unroll
    for (int i = 0; i < 4; ++i) {
        v[i] = xr[t + 256 * i];
        m = fmaxf(m, fmaxf(fmaxf(fabsf(v[i].x), fabsf(v[i].y)),
                           fmaxf(fabsf(v[i].z), fabsf(v[i].w))));
    }
#pragma unroll
    for (int off = 32; off > 0; off >>= 1) m = fmaxf(m, __shfl_xor(m, off));
    __shared__ float wm[4];
    if ((t & 63) == 0) wm[t >> 6] = m;
    __syncthreads();
    m = fmaxf(fmaxf(wm[0], wm[1]), fmaxf(wm[2], wm[3]));
    m = fmaxf(m, 1e-5f);                  // clip(max, EPS)
    const float scale = 127.0f / m;
    if (t == 0) inv_sx[row] = 1.0f / scale;

    int* qr = (int*)(qx + (size_t)row * K_DIM);
#pragma unroll
    for (int i = 0; i < 4; ++i) {
        int b0 = quant_act1(v[i].x, scale) & 255;
        int b1 = quant_act1(v[i].y, scale) & 255;
        int b2 = quant_act1(v[i].z, scale) & 255;
        int b3 = quant_act1(v[i].w, scale) & 255;
        qr[t + 256 * i] = b0 | (b1 << 8) | (b2 << 16) | (b3 << 24);
    }
}

// ---------------- weight abs-sum (deterministic two-stage) ----------------
__global__ __launch_bounds__(256) void wabs_partial_kernel(const float* __restrict__ w,
                                                           float* __restrict__ partials) {
    const int t = threadIdx.x;
    const size_t base = (size_t)blockIdx.x * 8192;   // float4 units
    const float4* w4 = (const float4*)w;
    float s = 0.0f;
#pragma unroll 8
    for (int i = 0; i < 32; ++i) {
        float4 v = w4[base + (size_t)i * 256 + t];
        s += fabsf(v.x) + fabsf(v.y) + fabsf(v.z) + fabsf(v.w);
    }
#pragma unroll
    for (int off = 32; off > 0; off >>= 1) s += __shfl_xor(s, off);
    __shared__ float wp[4];
    if ((t & 63) == 0) wp[t >> 6] = s;
    __syncthreads();
    if (t == 0) partials[blockIdx.x] = (wp[0] + wp[1]) + (wp[2] + wp[3]);
}

__global__ __launch_bounds__(256) void wfinal_kernel(const float* __restrict__ partials,
                                                     float* __restrict__ params) {
    __shared__ double sh[256];
    const int t = threadIdx.x;
    double s = 0.0;
    for (int i = t; i < 2048; i += 256) s += (double)partials[i];
    sh[t] = s;
    __syncthreads();
    for (int off = 128; off > 0; off >>= 1) {
        if (t < off) sh[t] += sh[t + off];
        __syncthreads();
    }
    if (t == 0) {
        float mean = (float)(sh[0] / 67108864.0);
        mean = fmaxf(mean, 1e-5f);        // clip(mean, EPS)
        float scale = 1.0f / mean;        // scale_w
        params[0] = scale;
        params[1] = 1.0f / scale;         // inv_sw
    }
}

// ---------------- weight quant: per-tensor ternary ----------------
__device__ __forceinline__ int quant_w1(float v, float s) {
    float q = rintf(v * s);
    q = fminf(1.0f, fmaxf(-1.0f, q));
    return (int)q;
}

__global__ __launch_bounds__(256) void w_quant_kernel(const float* __restrict__ w,
                                                      int8_t* __restrict__ qw,
                                                      const float* __restrict__ params) {
    const float scale = params[0];
    const int stride = gridDim.x * 256;
    const float4* w4 = (const float4*)w;
    int* q4 = (int*)qw;
    for (int g = blockIdx.x * 256 + threadIdx.x; g < 16777216; g += stride) {
        float4 v = w4[g];
        int b0 = quant_w1(v.x, scale) & 255;
        int b1 = quant_w1(v.y, scale) & 255;
        int b2 = quant_w1(v.z, scale) & 255;
        int b3 = quant_w1(v.w, scale) & 255;
        q4[g] = b0 | (b1 << 8) | (b2 << 16) | (b3 << 24);
    }
}

// ---------------- int8 GEMM: 256x256, m201-style 2-phase/K-step, 16 MFMA per cluster ----
// 8 waves (2M x 4N), per-wave 128x64 output, mfma_i32_16x16x64_i8 (verified layout).
// 4-slot LDS ring (slot = ks&3), stage 3 ahead. Per K-step t:
//   P1 { read A-lo(4)+B(4) of slot t | GLD A(t+3) | barrier | lgkm(0) | 16 MFMA | barrier }
//   P2 { read A-hi(4); B reused in regs | GLD B(t+3) | vmcnt(8) | barrier | lgkm(0) |
//        16 MFMA | barrier }
// vmcnt(8): 12 outstanding (t+1,t+2,t+3) minus 8 => K-step t+1 landed; barrier publishes.
// Never vmcnt(0) until the 3-step tail (8/4/0/none). GLD(t+3) only after the barrier that
// follows all waves' lgkm-drained reads of that slot (reuse distance 4).
// 16B-chunk XOR swizzle on global source + ds_read addr (round-1/4 verified: 0 conflicts).
__global__ __launch_bounds__(512, 2) void gemm_i8_kernel(const int8_t* __restrict__ qx,
                                                         const int8_t* __restrict__ qw,
                                                         const float* __restrict__ inv_sx,
                                                         const float* __restrict__ params,
                                                         const float* __restrict__ bias,
                                                         float* __restrict__ y) {
    __shared__ __align__(16) int8_t As[4][16384];
    __shared__ __align__(16) int8_t Bs[4][16384];
    int8_t* AsB = &As[0][0];
    int8_t* BsB = &Bs[0][0];

    const int tid = threadIdx.x;
    const int lane = tid & 63;
    const int w = tid >> 6;           // wave 0..7
    const int wr = w >> 2;            // 0..1  (M half)
    const int wc = w & 3;             // 0..3  (N quarter)
    const int wbase = w * 1024;       // wave-uniform LDS staging base (64 lanes x 16B)

    // XCD-aware bijective swizzle: 2048 blocks, 8 XCDs
    const int bid = blockIdx.x;
    const int swz = (bid & 7) * 256 + (bid >> 3);
    const int bn = swz & 63;          // 64 n-blocks
    const int bm = swz >> 6;          // 32 m-blocks

    const size_t arow0 = (size_t)bm * 256;
    const size_t brow0 = (size_t)bn * 256;

    // staging addressing: 512 chunks of 16B per 128-row half; thread tid -> chunk tid
    const int r0 = tid >> 2;                       // row 0..127 within half
    const int kc0 = (tid & 3) ^ ((r0 >> 1) & 3);   // swizzled k-slot (involution)
    const int8_t* gA0 = qx + (arow0 + r0) * K_DIM + kc0 * 16;
    const int8_t* gA1 = gA0 + (size_t)128 * K_DIM;
    const int8_t* gB0 = qw + (brow0 + r0) * K_DIM + kc0 * 16;
    const int8_t* gB1 = gB0 + (size_t)128 * K_DIM;

#define GLD(g, l)                                                                        \
    __builtin_amdgcn_global_load_lds((const __attribute__((address_space(1))) void*)(g), \
                                     (__attribute__((address_space(3))) void*)(l), 16, 0, 0)

    // fragment ds_read offsets (within one 16KB slot) — verified 16x16x64 layout
    const int ksub = lane >> 4;       // 16B k-chunk 0..3
    const int lrow = lane & 15;
    int aoff[8], boff[4];
#pragma unroll
    for (int i = 0; i < 8; ++i) {
        int ra = wr * 128 + i * 16 + lrow;
        aoff[i] = ra * 64 + ((ksub ^ ((ra >> 1) & 3)) << 4);
    }
#pragma unroll
    for (int j = 0; j < 4; ++j) {
        int rb = wc * 64 + j * 16 + lrow;
        boff[j] = rb * 64 + ((ksub ^ ((rb >> 1) & 3)) << 4);
    }

    v4i acc[8][4];
#pragma unroll
    for (int i = 0; i < 8; ++i)
#pragma unroll
        for (int j = 0; j < 4; ++j) acc[i][j] = (v4i){0, 0, 0, 0};

    v4i a[4], b[4];

#define SB() __builtin_amdgcn_sched_barrier(0)
#define BARR() __builtin_amdgcn_s_barrier()
#define LGKM0()                                                  \
    do {                                                         \
        asm volatile("s_waitcnt lgkmcnt(0)" ::: "memory");       \
        __builtin_amdgcn_sched_barrier(0);                       \
    } while (0)
#define VM8() asm volatile("s_waitcnt vmcnt(8)" ::: "memory")
#define VM4() asm volatile("s_waitcnt vmcnt(4)" ::: "memory")
#define VM0() asm volatile("s_waitcnt vmcnt(0)" ::: "memory")

#define MF16(ILO)                                                              \
    do {                                                                       \
        __builtin_amdgcn_s_setprio(1);                                         \
        _Pragma("unroll") for (int _i = 0; _i < 4; ++_i)                       \
            _Pragma("unroll") for (int _j = 0; _j < 4; ++_j)                   \
                acc[(ILO) + _i][_j] = __builtin_amdgcn_mfma_i32_16x16x64_i8(   \
                    a[_i], b[_j], acc[(ILO) + _i][_j], 0, 0, 0);               \
        __builtin_amdgcn_s_setprio(0);                                         \
    } while (0)

// One K-step: compute slot CS; stage K-step FKS into slot FSL (A in P1, B in P2).
#define KS(CS, FKS, FSL, STG, VMSTMT)                                          \
    do {                                                                       \
        const int8_t* _pa = AsB + (CS) * 16384;                                \
        const int8_t* _pb = BsB + (CS) * 16384;                                \
        /* ---- P1: A-lo + B reads, stage A, MFMA lo ---- */                   \
        _Pragma("unroll") for (int _i = 0; _i < 4; ++_i)                       \
            a[_i] = *(const v4i*)(_pa + aoff[_i]);                             \
        _Pragma("unroll") for (int _j = 0; _j < 4; ++_j)                       \
            b[_j] = *(const v4i*)(_pb + boff[_j]);                             \
        if (STG) {                                                             \
            GLD(gA0 + (size_t)(FKS) * 64, AsB + (FSL) * 16384 + wbase);        \
            GLD(gA1 + (size_t)(FKS) * 64, AsB + (FSL) * 16384 + 8192 + wbase); \
        }                                                                      \
        SB();                                                                  \
        BARR();                                                                \
        LGKM0();                                                               \
        MF16(0);                                                               \
        SB();                                                                  \
        BARR();                                                                \
        /* ---- P2: A-hi reads (B reused), stage B, publish t+1, MFMA hi ---- */ \
        _Pragma("unroll") for (int _i = 0; _i < 4; ++_i)                       \
            a[_i] = *(const v4i*)(_pa + aoff[4 + _i]);                         \
        if (STG) {                                                             \
            GLD(gB0 + (size_t)(FKS) * 64, BsB + (FSL) * 16384 + wbase);        \
            GLD(gB1 + (size_t)(FKS) * 64, BsB + (FSL) * 16384 + 8192 + wbase); \
        }                                                                      \
        VMSTMT;                                                                \
        SB();                                                                  \
        BARR();                                                                \
        LGKM0();                                                               \
        MF16(4);                                                               \
        SB();                                                                  \
        BARR();                                                                \
    } while (0)

    // prologue: stage K-steps 0,1,2 (A0,A1,B0,B1 each — same order as steady state);
    // vmcnt(8) proves K-step 0; barrier publishes slot 0.
    GLD(gA0, AsB + wbase);
    GLD(gA1, AsB + 8192 + wbase);
    GLD(gB0, BsB + wbase);
    GLD(gB1, BsB + 8192 + wbase);
    GLD(gA0 + 64, AsB + 16384 + wbase);
    GLD(gA1 + 64, AsB + 16384 + 8192 + wbase);
    GLD(gB0 + 64, BsB + 16384 + wbase);
    GLD(gB1 + 64, BsB + 16384 + 8192 + wbase);
    GLD(gA0 + 128, AsB + 2 * 16384 + wbase);
    GLD(gA1 + 128, AsB + 2 * 16384 + 8192 + wbase);
    GLD(gB0 + 128, BsB + 2 * 16384 + wbase);
    GLD(gB1 + 128, BsB + 2 * 16384 + 8192 + wbase);
    VM8();
    SB();
    BARR();

    // main loop: j=0..14, K-steps 4j..4j+3, staging 4j+3..4j+6 (slots 3,0,1,2)
#pragma unroll 1
    for (int j = 0; j < 15; ++j) {
        const int tb = 4 * j;
        KS(0, tb + 3, 3, 1, VM8());
        KS(1, tb + 4, 0, 1, VM8());
        KS(2, tb + 5, 1, 1, VM8());
        KS(3, tb + 6, 2, 1, VM8());
    }
    // tail: t=60 stages 63; then drain 8->4->0->none
    KS(0, 63, 3, 1, VM8());        // t=60: proves 61
    KS(1, 0, 0, 0, VM4());         // t=61: proves 62
    KS(2, 0, 0, 0, VM0());         // t=62: proves 63
    KS(3, 0, 0, 0, (void)0);       // t=63

    // epilogue: y = acc * inv_sx[row] * inv_sw + bias[col]  (verified 16x16 C/D layout)
    const float invsw = params[1];
    const int rl = (lane >> 4) * 4;
#pragma unroll
    for (int i = 0; i < 8; ++i) {
        const int grow_base = (int)arow0 + wr * 128 + i * 16 + rl;
        float isx[4];
#pragma unroll
        for (int r = 0; r < 4; ++r) isx[r] = inv_sx[grow_base + r] * invsw;
#pragma unroll
        for (int j = 0; j < 4; ++j) {
            const int gcol = (int)brow0 + wc * 64 + j * 16 + lrow;
            const float bb = bias[gcol];
#pragma unroll
            for (int r = 0; r < 4; ++r) {
                y[(size_t)(grow_base + r) * N_COLS + gcol] =
                    (float)acc[i][j][r] * isx[r] + bb;
            }
        }
    }
#undef GLD
#undef SB
#undef BARR
#undef LGKM0
#undef VM8
#undef VM4
#undef VM0
#undef MF16
#undef KS
}

// ---------------- launch ----------------
extern "C" void kernel_launch(void* const* d_in, const int* in_sizes, int n_in,
                              void* d_out, int out_size, void* d_ws, size_t ws_size,
                              hipStream_t stream) {
    const float* x    = (const float*)d_in[0];
    const float* wt   = (const float*)d_in[1];
    const float* bias = (const float*)d_in[2];
    float* y = (float*)d_out;

    if (ws_size < WS_NEED) return;

    char* ws = (char*)d_ws;
    float* partials = (float*)(ws + WS_PARTIALS);
    float* params   = (float*)(ws + WS_PARAMS);
    float* inv_sx   = (float*)(ws + WS_INVSX);
    int8_t* qx = (int8_t*)(ws + WS_QX);
    int8_t* qw = (int8_t*)(ws + WS_QW);

    hipLaunchKernelGGL(act_quant_kernel,   dim3(8192), dim3(256), 0, stream, x, qx, inv_sx);
    hipLaunchKernelGGL(wabs_partial_kernel,dim3(2048), dim3(256), 0, stream, wt, partials);
    hipLaunchKernelGGL(wfinal_kernel,      dim3(1),    dim3(256), 0, stream, partials, params);
    hipLaunchKernelGGL(w_quant_kernel,     dim3(4096), dim3(256), 0, stream, wt, qw, params);
    hipLaunchKernelGGL(gemm_i8_kernel,     dim3(2048), dim3(512), 0, stream,
                       qx, qw, inv_sx, params, bias, y);
}